// Round 1
// baseline (237.117 us; speedup 1.0000x reference)
//
#include <hip/hip_runtime.h>
#include <hip/hip_bf16.h>
#include <cstdint>

// ---------- types ----------
typedef __bf16 bf8 __attribute__((ext_vector_type(8)));
typedef __bf16 bf4 __attribute__((ext_vector_type(4)));
typedef float  f4  __attribute__((ext_vector_type(4)));

typedef const void __attribute__((address_space(1)))* as1_cvp;
typedef void       __attribute__((address_space(3)))* as3_vp;

#define NEG_INF_F 1000000000000.0f

__device__ __forceinline__ void lds_load16(const __bf16* g, __bf16* l) {
    // async global->LDS, 16B per lane; LDS dst = wave-uniform base + lane*16
    __builtin_amdgcn_global_load_lds((as1_cvp)g, (as3_vp)l, 16, 0, 0);
}

// ---------- shared MFMA GEMM core (used by proj) ----------
// C(128x128) += A(128xK) * Bt(128xK)^T   (both operands k-contiguous, bf16)
// block = 256 threads = 4 waves (2x2 of 64x64), BK=32, 16x16x32 bf16 MFMA.
__device__ __forceinline__ void gemm_tile_core(
    const __bf16* __restrict__ Atile, const __bf16* __restrict__ Btile,
    int lda, int ldb, int Ktot,
    __bf16* sA, __bf16* sB, f4 acc[4][4])
{
    const int t    = threadIdx.x;
    const int wave = t >> 6;
    const int lane = t & 63;
    const int quad = lane >> 4;
    const int m16  = lane & 15;
    const int wm   = (wave >> 1) * 64;
    const int wn   = (wave & 1) * 64;

    for (int k0 = 0; k0 < Ktot; k0 += 32) {
        __syncthreads();   // previous compute done before LDS overwrite
#pragma unroll
        for (int i = 0; i < 2; ++i) {
            const int f   = i * 256 + t;      // 16B chunk id, 0..511
            const int row = f >> 2;           // 4 chunks per 32-elem row
            const int ch  = (f & 3) * 8;      // elem offset in row
            lds_load16(Atile + (size_t)row * lda + k0 + ch,
                       sA + (i * 256 + wave * 64) * 8);
            lds_load16(Btile + (size_t)row * ldb + k0 + ch,
                       sB + (i * 256 + wave * 64) * 8);
        }
        __syncthreads();   // drains vmcnt -> LDS visible

        bf8 af[4], bfr[4];
#pragma unroll
        for (int mi = 0; mi < 4; ++mi)
            af[mi] = *(const bf8*)(sA + (wm + mi * 16 + m16) * 32 + quad * 8);
#pragma unroll
        for (int ni = 0; ni < 4; ++ni)
            bfr[ni] = *(const bf8*)(sB + (wn + ni * 16 + m16) * 32 + quad * 8);
#pragma unroll
        for (int mi = 0; mi < 4; ++mi)
#pragma unroll
            for (int ni = 0; ni < 4; ++ni)
                acc[mi][ni] = __builtin_amdgcn_mfma_f32_16x16x32_bf16(
                    af[mi], bfr[ni], acc[mi][ni], 0, 0, 0);
    }
}

// ---------- kernel 1: cast A fp32 -> bf16 ----------
__global__ __launch_bounds__(256) void cast_a_kernel(
    const float* __restrict__ in, __bf16* __restrict__ out, int n4)
{
    int idx = blockIdx.x * 256 + threadIdx.x;
    if (idx < n4) {
        const float4 v = reinterpret_cast<const float4*>(in)[idx];
        bf4 o = { (__bf16)v.x, (__bf16)v.y, (__bf16)v.z, (__bf16)v.w };
        reinterpret_cast<bf4*>(out)[idx] = o;
    }
}

// ---------- kernel 2: W (768x1152) -> Wt bf16 (1152x768) ----------
__global__ __launch_bounds__(256) void transpose_w_kernel(
    const float* __restrict__ W, __bf16* __restrict__ Wt)
{
    __shared__ __bf16 tile[32][33];
    const int n0 = blockIdx.x * 32;
    const int k0 = blockIdx.y * 32;
    const int tx = threadIdx.x & 31;
    const int ty = threadIdx.x >> 5;   // 0..7
#pragma unroll
    for (int r = 0; r < 32; r += 8)
        tile[ty + r][tx] = (__bf16)W[(size_t)(k0 + ty + r) * 1152 + n0 + tx];
    __syncthreads();
#pragma unroll
    for (int r = 0; r < 32; r += 8)
        Wt[(size_t)(n0 + ty + r) * 768 + k0 + tx] = tile[tx][ty + r];
}

// ---------- kernel 3: proj GEMM + bias + RoPE -> q/k bf16 (b,e,s,64) ----------
__global__ __launch_bounds__(256) void proj_rope_kernel(
    const __bf16* __restrict__ A,    // 8192 x 768
    const __bf16* __restrict__ Wt,   // 1152 x 768
    const float*  __restrict__ bias, // 1152
    __bf16* __restrict__ qbuf, __bf16* __restrict__ kbuf)
{
    __shared__ __bf16 sA[128 * 32];
    __shared__ __bf16 sB[128 * 32];
    f4 acc[4][4] = {};

    const int rowTile = blockIdx.y * 128;   // over M=8192
    const int colTile = blockIdx.x * 128;   // over N=1152
    gemm_tile_core(A + (size_t)rowTile * 768, Wt + (size_t)colTile * 768,
                   768, 768, 768, sA, sB, acc);

    const int t = threadIdx.x, wave = t >> 6, lane = t & 63;
    const int quad = lane >> 4, m16 = lane & 15;
    const int wm = (wave >> 1) * 64, wn = (wave & 1) * 64;

#pragma unroll
    for (int ni = 0; ni < 4; ++ni) {
        const int gc = colTile + wn + ni * 16 + m16;   // 0..1151
        const float bv = bias[gc];
        const int e  = gc >> 7;          // ent 0..8
        const int d  = gc & 63;          // dim within q/k
        const int qk = (gc >> 6) & 1;    // 0=q, 1=k
        // theta_i = 10000^{-i/32} = 2^{-i*log2(10000)/32}
        const float theta = exp2f((float)(d >> 1) * -0.4152410118609203f);
        const float sgn = (d & 1) ? 1.0f : -1.0f;
        __bf16* dst = qk ? kbuf : qbuf;
#pragma unroll
        for (int mi = 0; mi < 4; ++mi) {
#pragma unroll
            for (int r = 0; r < 4; ++r) {
                const int gm = rowTile + wm + mi * 16 + quad * 4 + r;
                const int bb = gm >> 9;      // batch
                const int s  = gm & 511;     // position
                float v = acc[mi][ni][r] + bv;
                // pair partner (col ^ 1) lives in lane ^ 1 (C-layout col = lane&15)
                float p = __shfl_xor(v, 1);
                float sn, cs;
                __sincosf((float)s * theta, &sn, &cs);
                float o = v * cs + sgn * p * sn;
                dst[(size_t)(((bb * 9 + e) * 512 + s)) * 64 + d] = (__bf16)o;
            }
        }
    }
}

// ---------- kernel 4: barrier-free streaming logits ----------
// grid (4, 144): block = (rowTile, be). No LDS, no __syncthreads.
// Each wave owns 64 rows x 256 cols: Q fragments live in registers (loaded
// once); K fragments are loaded straight from global (64 KB/be -> L2-hit).
// Swapped-operand MFMA: acc = mfma(K_frag, Q_frag) puts n on the reg index
// (n = quad*4+r) and m on lane&15 -> each thread stores a full float4 along n.
__global__ __launch_bounds__(256, 3) void logits_kernel(
    const __bf16* __restrict__ qbuf, const __bf16* __restrict__ kbuf,
    const float* __restrict__ amask, float* __restrict__ out)
{
    const int t    = threadIdx.x;
    const int wave = t >> 6;
    const int lane = t & 63;
    const int quad = lane >> 4;
    const int m16  = lane & 15;
    const int wm   = (wave >> 1) * 64;   // row offset within the 128-row tile
    const int ncol = (wave & 1) * 256;   // column half owned by this wave

    const int be = blockIdx.y;           // 0..143
    const int b  = be / 9;
    const int rowTile = blockIdx.x * 128;

    const __bf16* Qg = qbuf + (size_t)be * 512 * 64 + (size_t)(rowTile + wm) * 64;
    const __bf16* Kg = kbuf + (size_t)be * 512 * 64;

    // ---- Q fragments: resident in registers for the whole kernel ----
    // B-slot layout: col = lane&15 (Q row), k = quad*8 (+ kp*32)
    bf8 af[2][4];
#pragma unroll
    for (int kp = 0; kp < 2; ++kp)
#pragma unroll
        for (int mi = 0; mi < 4; ++mi)
            af[kp][mi] = *reinterpret_cast<const bf8*>(
                Qg + (mi * 16 + m16) * 64 + kp * 32 + quad * 8);

    const float* amr  = amask + b * 512;
    float*       outw = out + ((size_t)(be * 512 + rowTile + wm) << 9);

#pragma unroll 1
    for (int c = 0; c < 4; ++c) {
        const int n0 = ncol + c * 64;
        const __bf16* Kc = Kg + (size_t)n0 * 64;

        // K fragments straight from global (L2-resident, 16 rows x 64B/instr)
        bf8 bfr[2][4];
#pragma unroll
        for (int kp = 0; kp < 2; ++kp)
#pragma unroll
            for (int ni = 0; ni < 4; ++ni)
                bfr[kp][ni] = *reinterpret_cast<const bf8*>(
                    Kc + (ni * 16 + m16) * 64 + kp * 32 + quad * 8);

        f4 acc[4][4] = {};
#pragma unroll
        for (int kp = 0; kp < 2; ++kp)
#pragma unroll
            for (int mi = 0; mi < 4; ++mi)
#pragma unroll
                for (int ni = 0; ni < 4; ++ni)
                    acc[mi][ni] = __builtin_amdgcn_mfma_f32_16x16x32_bf16(
                        bfr[kp][ni], af[kp][mi], acc[mi][ni], 0, 0, 0);

        // ---- epilogue: float4 stores along n ----
#pragma unroll
        for (int ni = 0; ni < 4; ++ni) {
            const int nq = n0 + ni * 16 + quad * 4;
            const float4 pv = *reinterpret_cast<const float4*>(amr + nq);
#pragma unroll
            for (int mi = 0; mi < 4; ++mi) {
                const int m = rowTile + wm + mi * 16 + m16;
                const f4 a = acc[mi][ni];
                float4 res;
                float* rp = &res.x;
                const float pp[4] = { pv.x, pv.y, pv.z, pv.w };
#pragma unroll
                for (int r = 0; r < 4; ++r) {
                    float v = a[r] * pp[r] - (1.0f - pp[r]) * NEG_INF_F;
                    if (nq + r < m) v -= NEG_INF_F;   // tril(-1) causal-past mask
                    rp[r] = v * 0.125f;
                }
                *reinterpret_cast<float4*>(
                    outw + (((size_t)(mi * 16 + m16)) << 9) + nq) = res;
            }
        }
    }
}

// ---------- launch ----------
extern "C" void kernel_launch(void* const* d_in, const int* in_sizes, int n_in,
                              void* d_out, int out_size, void* d_ws, size_t ws_size,
                              hipStream_t stream) {
    const float* lhs   = (const float*)d_in[0];  // 16*512*768
    const float* amask = (const float*)d_in[1];  // 16*512
    const float* W     = (const float*)d_in[2];  // 768*1152
    const float* bias  = (const float*)d_in[3];  // 1152
    float* out = (float*)d_out;

    char* ws = (char*)d_ws;
    __bf16* Abf = (__bf16*)ws;                       // 8192*768*2   = 12,582,912 B
    __bf16* Wt  = (__bf16*)(ws + 12582912);          // 1152*768*2   =  1,769,472 B
    __bf16* qb  = (__bf16*)(ws + 14352384);          // 144*512*64*2 =  9,437,184 B
    __bf16* kb  = (__bf16*)(ws + 23789568);          // 144*512*64*2 =  9,437,184 B

    cast_a_kernel<<<6144, 256, 0, stream>>>(lhs, Abf, 1572864);      // 6291456/4
    transpose_w_kernel<<<dim3(36, 24), 256, 0, stream>>>(W, Wt);
    proj_rope_kernel<<<dim3(9, 64), 256, 0, stream>>>(Abf, Wt, bias, qb, kb);
    logits_kernel<<<dim3(4, 144), 256, 0, stream>>>(qb, kb, amask, out);
}

// Round 2
// 226.852 us; speedup vs baseline: 1.0453x; 1.0453x over previous
//
#include <hip/hip_runtime.h>
#include <hip/hip_bf16.h>
#include <cstdint>

// ---------- types ----------
typedef __bf16 bf8 __attribute__((ext_vector_type(8)));
typedef __bf16 bf4 __attribute__((ext_vector_type(4)));
typedef float  f4  __attribute__((ext_vector_type(4)));

typedef const void __attribute__((address_space(1)))* as1_cvp;
typedef void       __attribute__((address_space(3)))* as3_vp;

#define NEG_INF_F 1000000000000.0f

__device__ __forceinline__ void lds_load16(const __bf16* g, __bf16* l) {
    // async global->LDS, 16B per lane; LDS dst = wave-uniform base + lane*16
    __builtin_amdgcn_global_load_lds((as1_cvp)g, (as3_vp)l, 16, 0, 0);
}

// ---------- MFMA GEMM core (proj), SWAPPED operand order ----------
// C(128x128) += A(128xK) * Bt(128xK)^T, bf16, BK=32, 4 waves (2x2 of 64x64).
// mfma(bfr, af): C row m = lane&15 (A-row), C col n = quad*4 + reg (Bt-row).
// (Layout HW-verified: identical swapped form passes in logits_kernel.)
__device__ __forceinline__ void gemm_tile_core_swapped(
    const __bf16* __restrict__ Atile, const __bf16* __restrict__ Btile,
    int lda, int ldb, int Ktot,
    __bf16* sA, __bf16* sB, f4 acc[4][4])
{
    const int t    = threadIdx.x;
    const int wave = t >> 6;
    const int lane = t & 63;
    const int quad = lane >> 4;
    const int m16  = lane & 15;
    const int wm   = (wave >> 1) * 64;
    const int wn   = (wave & 1) * 64;

    for (int k0 = 0; k0 < Ktot; k0 += 32) {
        __syncthreads();   // previous compute done before LDS overwrite
#pragma unroll
        for (int i = 0; i < 2; ++i) {
            const int f   = i * 256 + t;      // 16B chunk id, 0..511
            const int row = f >> 2;           // 4 chunks per 32-elem row
            const int ch  = (f & 3) * 8;      // elem offset in row
            lds_load16(Atile + (size_t)row * lda + k0 + ch,
                       sA + (i * 256 + wave * 64) * 8);
            lds_load16(Btile + (size_t)row * ldb + k0 + ch,
                       sB + (i * 256 + wave * 64) * 8);
        }
        __syncthreads();   // drains vmcnt -> LDS visible

        bf8 af[4], bfr[4];
#pragma unroll
        for (int mi = 0; mi < 4; ++mi)
            af[mi] = *(const bf8*)(sA + (wm + mi * 16 + m16) * 32 + quad * 8);
#pragma unroll
        for (int ni = 0; ni < 4; ++ni)
            bfr[ni] = *(const bf8*)(sB + (wn + ni * 16 + m16) * 32 + quad * 8);
#pragma unroll
        for (int mi = 0; mi < 4; ++mi)
#pragma unroll
            for (int ni = 0; ni < 4; ++ni)
                acc[mi][ni] = __builtin_amdgcn_mfma_f32_16x16x32_bf16(
                    bfr[ni], af[mi], acc[mi][ni], 0, 0, 0);
    }
}

// ---------- kernel 1: fused cast (A fp32->bf16) + W transpose ----------
__global__ __launch_bounds__(256) void prep_kernel(
    const float* __restrict__ lhs, __bf16* __restrict__ Abf,
    const float* __restrict__ W,   __bf16* __restrict__ Wt)
{
    __shared__ __bf16 tile[32][33];
    const int t  = threadIdx.x;
    int bx = blockIdx.x;
    if (bx < 6144) {
        // cast: 6144 * 256 * 4 floats = exactly 16*512*768
        const int idx = bx * 256 + t;
        const float4 v = reinterpret_cast<const float4*>(lhs)[idx];
        bf4 o = { (__bf16)v.x, (__bf16)v.y, (__bf16)v.z, (__bf16)v.w };
        reinterpret_cast<bf4*>(Abf)[idx] = o;
    } else {
        // transpose W (768x1152) -> Wt bf16 (1152x768)
        bx -= 6144;                       // 0..863 = 36*24
        const int n0 = (bx % 36) * 32;
        const int k0 = (bx / 36) * 32;
        const int tx = t & 31;
        const int ty = t >> 5;            // 0..7
#pragma unroll
        for (int r = 0; r < 32; r += 8)
            tile[ty + r][tx] = (__bf16)W[(size_t)(k0 + ty + r) * 1152 + n0 + tx];
        __syncthreads();
#pragma unroll
        for (int r = 0; r < 32; r += 8)
            Wt[(size_t)(n0 + ty + r) * 768 + k0 + tx] = tile[tx][ty + r];
    }
}

// ---------- kernel 2: proj GEMM + bias + RoPE -> q/k bf16 (b,e,s,64) ----------
// Swapped-operand layout: output col n = colTile+wn+ni*16+quad*4+r lands on the
// accumulator reg index -> RoPE pair (d,d^1) is IN-THREAD (no shfl), bias is a
// float4 load, and q/k store is one 8B bf16x4 per (mi,ni).
__global__ __launch_bounds__(256) void proj_rope_kernel(
    const __bf16* __restrict__ A,    // 8192 x 768
    const __bf16* __restrict__ Wt,   // 1152 x 768
    const float*  __restrict__ bias, // 1152
    __bf16* __restrict__ qbuf, __bf16* __restrict__ kbuf)
{
    __shared__ __bf16 sA[128 * 32];
    __shared__ __bf16 sB[128 * 32];
    f4 acc[4][4] = {};

    const int rowTile = blockIdx.y * 128;   // over M=8192
    const int colTile = blockIdx.x * 128;   // over N=1152
    gemm_tile_core_swapped(A + (size_t)rowTile * 768, Wt + (size_t)colTile * 768,
                           768, 768, 768, sA, sB, acc);

    const int t = threadIdx.x, wave = t >> 6, lane = t & 63;
    const int quad = lane >> 4, m16 = lane & 15;
    const int wm = (wave >> 1) * 64, wn = (wave & 1) * 64;

#pragma unroll
    for (int ni = 0; ni < 4; ++ni) {
        const int gc0 = colTile + wn + ni * 16 + quad * 4;  // 4-aligned col base
        const int e   = gc0 >> 7;          // ent 0..8
        const int d0  = gc0 & 63;          // dim base within q/k (mult of 4)
        const int qk  = (gc0 >> 6) & 1;    // 0=q, 1=k
        const float4 bv = *reinterpret_cast<const float4*>(bias + gc0);
        // theta_i = 10000^{-i/32} = 2^{-i*log2(10000)/32}
        const float th0 = exp2f((float)(d0 >> 1)       * -0.4152410118609203f);
        const float th1 = exp2f((float)((d0 >> 1) + 1) * -0.4152410118609203f);
        __bf16* base = (qk ? kbuf : qbuf);
#pragma unroll
        for (int mi = 0; mi < 4; ++mi) {
            const int gm = rowTile + wm + mi * 16 + m16;
            const int bb = gm >> 9;      // batch
            const int s  = gm & 511;     // position
            const float sf = (float)s;
            float v0 = acc[mi][ni][0] + bv.x;
            float v1 = acc[mi][ni][1] + bv.y;
            float v2 = acc[mi][ni][2] + bv.z;
            float v3 = acc[mi][ni][3] + bv.w;
            float sn0, cs0, sn1, cs1;
            __sincosf(sf * th0, &sn0, &cs0);
            __sincosf(sf * th1, &sn1, &cs1);
            bf4 o = { (__bf16)(v0 * cs0 - v1 * sn0),
                      (__bf16)(v1 * cs0 + v0 * sn0),
                      (__bf16)(v2 * cs1 - v3 * sn1),
                      (__bf16)(v3 * cs1 + v2 * sn1) };
            *reinterpret_cast<bf4*>(
                base + ((size_t)((bb * 9 + e) * 512 + s)) * 64 + d0) = o;
        }
    }
}

// ---------- kernel 3: barrier-free streaming logits with causal-tile skip ----
// grid (4, 144). No LDS, no __syncthreads. Q frags in registers; K frags
// loaded straight from global (64 KB/be -> L2-hit). Swapped-operand MFMA.
// Tiles fully below the diagonal (all n < m) skip K-loads+MFMA: the -1e12
// subtraction absorbs acc exactly in f32 (ulp at 1e12 = 65536 >> |acc|),
// so the stored bits match the reference bit-for-bit.
__global__ __launch_bounds__(256, 3) void logits_kernel(
    const __bf16* __restrict__ qbuf, const __bf16* __restrict__ kbuf,
    const float* __restrict__ amask, float* __restrict__ out)
{
    const int t    = threadIdx.x;
    const int wave = t >> 6;
    const int lane = t & 63;
    const int quad = lane >> 4;
    const int m16  = lane & 15;
    const int wm   = (wave >> 1) * 64;   // row offset within the 128-row tile
    const int ncol = (wave & 1) * 256;   // column half owned by this wave

    const int be = blockIdx.y;           // 0..143
    const int b  = be / 9;
    const int rowTile = blockIdx.x * 128;
    const int rowbase = rowTile + wm;

    // number of fully-masked 64-col chunks (prefix in c): chunk masked iff
    // ncol + 64c + 63 < rowbase  <=>  c < (rowbase - ncol)/64  (both 64-aligned)
    int c0 = (rowbase - ncol) >> 6;
    c0 = c0 < 0 ? 0 : (c0 > 4 ? 4 : c0);

    const __bf16* Qg = qbuf + (size_t)be * 512 * 64 + (size_t)rowbase * 64;
    const __bf16* Kg = kbuf + (size_t)be * 512 * 64;

    // ---- Q fragments: resident in registers for the whole kernel ----
    bf8 af[2][4];
#pragma unroll
    for (int kp = 0; kp < 2; ++kp)
#pragma unroll
        for (int mi = 0; mi < 4; ++mi)
            af[kp][mi] = *reinterpret_cast<const bf8*>(
                Qg + (mi * 16 + m16) * 64 + kp * 32 + quad * 8);

    const float* amr  = amask + b * 512;
    float*       outw = out + ((size_t)(be * 512 + rowbase) << 9);

#pragma unroll
    for (int c = 0; c < 4; ++c) {
        const int n0 = ncol + c * 64;
        if (c >= c0) {
            // ---- live tile: K frags from global, MFMA, full epilogue ----
            const __bf16* Kc = Kg + (size_t)n0 * 64;
            bf8 bfr[2][4];
#pragma unroll
            for (int kp = 0; kp < 2; ++kp)
#pragma unroll
                for (int ni = 0; ni < 4; ++ni)
                    bfr[kp][ni] = *reinterpret_cast<const bf8*>(
                        Kc + (ni * 16 + m16) * 64 + kp * 32 + quad * 8);

            f4 acc[4][4] = {};
#pragma unroll
            for (int kp = 0; kp < 2; ++kp)
#pragma unroll
                for (int mi = 0; mi < 4; ++mi)
#pragma unroll
                    for (int ni = 0; ni < 4; ++ni)
                        acc[mi][ni] = __builtin_amdgcn_mfma_f32_16x16x32_bf16(
                            bfr[kp][ni], af[kp][mi], acc[mi][ni], 0, 0, 0);

#pragma unroll
            for (int ni = 0; ni < 4; ++ni) {
                const int nq = n0 + ni * 16 + quad * 4;
                const float4 pv = *reinterpret_cast<const float4*>(amr + nq);
                const float pp[4] = { pv.x, pv.y, pv.z, pv.w };
#pragma unroll
                for (int mi = 0; mi < 4; ++mi) {
                    const int m = rowbase + mi * 16 + m16;
                    const f4 a = acc[mi][ni];
                    float4 res;
                    float* rp = &res.x;
#pragma unroll
                    for (int r = 0; r < 4; ++r) {
                        float v = a[r] * pp[r] - (1.0f - pp[r]) * NEG_INF_F;
                        if (nq + r < m) v -= NEG_INF_F;   // tril(-1) mask
                        rp[r] = v * 0.125f;
                    }
                    *reinterpret_cast<float4*>(
                        outw + (((size_t)(mi * 16 + m16)) << 9) + nq) = res;
                }
            }
        } else {
            // ---- fully-masked tile: constant epilogue (acc == 0) ----
#pragma unroll
            for (int ni = 0; ni < 4; ++ni) {
                const int nq = n0 + ni * 16 + quad * 4;
                const float4 pv = *reinterpret_cast<const float4*>(amr + nq);
                const float pp[4] = { pv.x, pv.y, pv.z, pv.w };
                float4 res;
                float* rp = &res.x;
#pragma unroll
                for (int r = 0; r < 4; ++r)
                    rp[r] = (-(1.0f - pp[r]) * NEG_INF_F - NEG_INF_F) * 0.125f;
#pragma unroll
                for (int mi = 0; mi < 4; ++mi)
                    *reinterpret_cast<float4*>(
                        outw + (((size_t)(mi * 16 + m16)) << 9) + nq) = res;
            }
        }
    }
}

// ---------- launch ----------
extern "C" void kernel_launch(void* const* d_in, const int* in_sizes, int n_in,
                              void* d_out, int out_size, void* d_ws, size_t ws_size,
                              hipStream_t stream) {
    const float* lhs   = (const float*)d_in[0];  // 16*512*768
    const float* amask = (const float*)d_in[1];  // 16*512
    const float* W     = (const float*)d_in[2];  // 768*1152
    const float* bias  = (const float*)d_in[3];  // 1152
    float* out = (float*)d_out;

    char* ws = (char*)d_ws;
    __bf16* Abf = (__bf16*)ws;                       // 8192*768*2   = 12,582,912 B
    __bf16* Wt  = (__bf16*)(ws + 12582912);          // 1152*768*2   =  1,769,472 B
    __bf16* qb  = (__bf16*)(ws + 14352384);          // 144*512*64*2 =  9,437,184 B
    __bf16* kb  = (__bf16*)(ws + 23789568);          // 144*512*64*2 =  9,437,184 B

    prep_kernel<<<7008, 256, 0, stream>>>(lhs, Abf, W, Wt);   // 6144 cast + 864 transpose
    proj_rope_kernel<<<dim3(9, 64), 256, 0, stream>>>(Abf, Wt, bias, qb, kb);
    logits_kernel<<<dim3(4, 144), 256, 0, stream>>>(qb, kb, amask, out);
}